// Round 21
// baseline (43.411 us; speedup 1.0000x reference)
//
#include <hip/hip_runtime.h>

// (min,+) DP, wave-specialized. R20 topology (best, 38.3us): 1 image/block,
// 7 waves, grid=512 (2/CU); wid3 = chain (SIMD3 pairs the two blocks'
// chains); 6 prep waves on SIMD0-2.
// NEW: tropical-factored chain. Substituting v_i = S_i + min(moff, m_i)
// into B and using fmin(a+x,b+x) = x + fmin(a,b) (exact), each row becomes
//   m_i = fmin(C_i, moff + D_i);  mm = scan_min(m3)
// with C_i, D_i precomputed OFF the carried path. Critical path/row:
// 1 dpp (moff) + 2 VALU + 6 dpp (scan)  — was ~8 dpp + 8 VALU.
// v never materialized (out = S.w + mm at row 255, lane 63).

#define HH 256
#define WW 256
#define CH 16          // rows per chunk
#define NCH 16         // chunks per image
#define NULLV 1e30f

template<int CTRL, int ROWM>
__device__ __forceinline__ float dpp_mov(float x, float oldv) {
    return __builtin_bit_cast(float, __builtin_amdgcn_update_dpp(
        __builtin_bit_cast(int, oldv), __builtin_bit_cast(int, x),
        CTRL, ROWM, 0xF, false));
}

// 64-lane inclusive min-scan: 6 fused in-place DPP steps (proven R18-R20).
__device__ __forceinline__ float wave_iscan_min(float x) {
    asm volatile(
        "s_nop 1\n\t"
        "v_min_f32_dpp %0, %0, %0 row_shr:1  row_mask:0xf bank_mask:0xf\n\t"
        "s_nop 1\n\t"
        "v_min_f32_dpp %0, %0, %0 row_shr:2  row_mask:0xf bank_mask:0xf\n\t"
        "s_nop 1\n\t"
        "v_min_f32_dpp %0, %0, %0 row_shr:4  row_mask:0xf bank_mask:0xf\n\t"
        "s_nop 1\n\t"
        "v_min_f32_dpp %0, %0, %0 row_shr:8  row_mask:0xf bank_mask:0xf\n\t"
        "s_nop 1\n\t"
        "v_min_f32_dpp %0, %0, %0 row_bcast:15 row_mask:0xa bank_mask:0xf\n\t"
        "s_nop 1\n\t"
        "v_min_f32_dpp %0, %0, %0 row_bcast:31 row_mask:0xc bank_mask:0xf"
        : "+v"(x));
    return x;
}

// 64-lane inclusive add-scan (prep only).
__device__ __forceinline__ float wave_iscan_add(float x) {
    asm volatile(
        "s_nop 1\n\t"
        "v_add_f32_dpp %0, %0, %0 row_shr:1  row_mask:0xf bank_mask:0xf bound_ctrl:0\n\t"
        "s_nop 1\n\t"
        "v_add_f32_dpp %0, %0, %0 row_shr:2  row_mask:0xf bank_mask:0xf bound_ctrl:0\n\t"
        "s_nop 1\n\t"
        "v_add_f32_dpp %0, %0, %0 row_shr:4  row_mask:0xf bank_mask:0xf bound_ctrl:0\n\t"
        "s_nop 1\n\t"
        "v_add_f32_dpp %0, %0, %0 row_shr:8  row_mask:0xf bank_mask:0xf bound_ctrl:0\n\t"
        "s_nop 1\n\t"
        "v_add_f32_dpp %0, %0, %0 row_bcast:15 row_mask:0xa bank_mask:0xf bound_ctrl:0\n\t"
        "s_nop 1\n\t"
        "v_add_f32_dpp %0, %0, %0 row_bcast:31 row_mask:0xc bank_mask:0xf bound_ctrl:0"
        : "+v"(x));
    return x;
}

__device__ __forceinline__ float softplus_f(float x) {
    float ax = fabsf(x);
    float t  = __expf(-ax);
    return fmaxf(x, 0.0f) + __logf(1.0f + t);
}

// full-row cumsum of softplus for one row; returns S at cols 4l..4l+3
__device__ __forceinline__ float4 prep_row(float4 c) {
    float t0 = softplus_f(c.x);
    float t1 = t0 + softplus_f(c.y);
    float t2 = t1 + softplus_f(c.z);
    float t3 = t2 + softplus_f(c.w);
    float s    = wave_iscan_add(t3);
    float soff = dpp_mov<0x138, 0xF>(s, 0.0f);  // wave_shr:1, lane0 -> 0
    return make_float4(soff + t0, soff + t1, soff + t2, soff + t3);
}

template<int NR>
__device__ __forceinline__ void load_rows(const float4* gp, int r0, float4* L) {
#pragma unroll
    for (int i = 0; i < NR; ++i) L[i] = gp[(size_t)(r0 + i) * 64];
}

template<int NR>
__device__ __forceinline__ void prep_store(const float4* L, float* dst, int lane) {
#pragma unroll
    for (int i = 0; i < NR; ++i)
        *reinterpret_cast<float4*>(&dst[i * WW + lane * 4]) = prep_row(L[i]);
}

template<int NR>
__device__ __forceinline__ void prep_run(const float4* gp, int row0,
                                         float* base0, float* base1, int lane) {
    float4 L[NR];
    load_rows<NR>(gp, CH + row0, L);           // chunk 1
    __syncthreads();                           // B0 (chunk 0 published by all)
    for (int k = 1; k < NCH; ++k) {
        float4 N[NR];
        if (k + 1 < NCH) load_rows<NR>(gp, (k + 1) * CH + row0, N);
        prep_store<NR>(L, (k & 1) ? base1 : base0, lane);
        __syncthreads();                       // Bk: chunk k ready
        if (k + 1 < NCH) {
#pragma unroll
            for (int i = 0; i < NR; ++i) L[i] = N[i];
        }
    }
}

__global__ __launch_bounds__(448, 2) void dp_kernel(const float* __restrict__ img,
                                                    float* __restrict__ out) {
    const int tid = threadIdx.x;
    const int wid = tid >> 6;                  // 0..6; wid3 = chain (SIMD3)
    const int lane = tid & 63;

    // [buffer][row][col] -> 32 KB
    __shared__ __align__(16) float sbuf[2][CH][WW];

    const float* gbase = img + (size_t)blockIdx.x * HH * WW;
    const float4* gp = reinterpret_cast<const float4*>(gbase) + lane;

    if (wid == 3) {
        // ---------------- chain wave (tropical-factored recurrence) ----------------
        {   // cooperative chunk-0: rows 0-1
            float4 C[2];
            load_rows<2>(gp, 0, C);
            prep_store<2>(C, &sbuf[0][0][0], lane);
        }
        __syncthreads();                       // B0: chunk 0 ready
        __builtin_amdgcn_s_setprio(1);

        float4 Sp;                              // previous row's S
        float m0, m1, m2, m3;                   // prev row in-lane prefix mins
        float mm;                               // prev row scan output
        float soffp;                            // shr(Sp.w)

        auto init_row0 = [&](const float4& S) {
            Sp = S; m0 = m1 = m2 = m3 = 0.0f; mm = 0.0f;
            soffp = dpp_mov<0x138, 0xF>(S.w, 0.0f);
        };

        auto row_step = [&](const float4& Sc) {
            // ---- off-path: factored coefficients ----
            float u0 = Sp.x + m0, u1 = Sp.y + m1, u2 = Sp.z + m2, u3 = Sp.w + m3;
            float c1 = fminf(u1, u0), c2 = fminf(u2, u1), c3 = fminf(u3, u2);
            float d0 = fminf(Sp.x, soffp);
            float d1 = fminf(Sp.y, Sp.x), d2 = fminf(Sp.z, Sp.y), d3 = fminf(Sp.w, Sp.z);
            float soffc = dpp_mov<0x138, 0xF>(Sc.w, 0.0f);   // P_0 (off-path)
            float e0 = u0 - soffc, e1 = c1 - Sc.x, e2 = c2 - Sc.y, e3 = c3 - Sc.z;
            float f0 = d0 - soffc, f1 = d1 - Sc.x, f2 = d2 - Sc.y, f3 = d3 - Sc.z;
            float C1 = fminf(e0, e1), C2 = fminf(C1, e2);
            float C3 = fminf(C1, fminf(e2, e3));
            float D1 = fminf(f0, f1), D2 = fminf(D1, f2);
            float D3 = fminf(D1, fminf(f2, f3));
            // ---- on-path: moff -> m -> scan ----
            float moff = dpp_mov<0x138, 0xF>(mm, NULLV);
            m0 = fminf(e0, moff + f0);
            m1 = fminf(C1, moff + D1);
            m2 = fminf(C2, moff + D2);
            m3 = fminf(C3, moff + D3);
            mm = wave_iscan_min(m3);
            Sp = Sc; soffp = soffc;
        };

#define RD4(P, buf, r0)                                                  \
    P##0 = *reinterpret_cast<const float4*>(&(buf)[(r0) + 0][lane * 4]); \
    P##1 = *reinterpret_cast<const float4*>(&(buf)[(r0) + 1][lane * 4]); \
    P##2 = *reinterpret_cast<const float4*>(&(buf)[(r0) + 2][lane * 4]); \
    P##3 = *reinterpret_cast<const float4*>(&(buf)[(r0) + 3][lane * 4]);
#define ST4(P) row_step(P##0); row_step(P##1); row_step(P##2); row_step(P##3);

        float4 A0, A1, A2, A3, B0, B1, B2, B3;

        // chunk 0 (rows 0..15; row-0 init)
        {
            const float(*buf)[WW] = sbuf[0];
            RD4(A, buf, 0); RD4(B, buf, 4);
            init_row0(A0);
            row_step(A1); row_step(A2); row_step(A3);
            RD4(A, buf, 8);
            ST4(B);
            RD4(B, buf, 12);
            ST4(A);
            ST4(B);
        }
        // chunks 1..15
        for (int k = 1; k < NCH; ++k) {
            __syncthreads();                   // Bk
            const float(*buf)[WW] = sbuf[k & 1];
            RD4(A, buf, 0); RD4(B, buf, 4);
            ST4(A);
            RD4(A, buf, 8);
            ST4(B);
            RD4(B, buf, 12);
            ST4(A);
            ST4(B);
        }
#undef RD4
#undef ST4
        // out = v3[col 255] = S.w + mm at lane 63
        if (lane == 63) out[blockIdx.x] = Sp.w + mm;
    } else {
        // ---------------- prep waves (wid 0,1,2,4,5,6) ----------------
        // coop chunk-0 split: wid0:2-4 wid1:5-7 wid2:8-10 wid4:11-12 wid5:13-14 wid6:15
        if (wid == 0) { float4 C[3]; load_rows<3>(gp,  2, C); prep_store<3>(C, &sbuf[0][ 2][0], lane); }
        else if (wid == 1) { float4 C[3]; load_rows<3>(gp,  5, C); prep_store<3>(C, &sbuf[0][ 5][0], lane); }
        else if (wid == 2) { float4 C[3]; load_rows<3>(gp,  8, C); prep_store<3>(C, &sbuf[0][ 8][0], lane); }
        else if (wid == 4) { float4 C[2]; load_rows<2>(gp, 11, C); prep_store<2>(C, &sbuf[0][11][0], lane); }
        else if (wid == 5) { float4 C[2]; load_rows<2>(gp, 13, C); prep_store<2>(C, &sbuf[0][13][0], lane); }
        else               { float4 C[1]; load_rows<1>(gp, 15, C); prep_store<1>(C, &sbuf[0][15][0], lane); }

        // steady rows: wid0:0-2 wid1:3-5 wid2:6-8 wid4:9-11 wid5:12-13 wid6:14-15
        if (wid == 0)      prep_run<3>(gp,  0, &sbuf[0][ 0][0], &sbuf[1][ 0][0], lane);
        else if (wid == 1) prep_run<3>(gp,  3, &sbuf[0][ 3][0], &sbuf[1][ 3][0], lane);
        else if (wid == 2) prep_run<3>(gp,  6, &sbuf[0][ 6][0], &sbuf[1][ 6][0], lane);
        else if (wid == 4) prep_run<3>(gp,  9, &sbuf[0][ 9][0], &sbuf[1][ 9][0], lane);
        else if (wid == 5) prep_run<2>(gp, 12, &sbuf[0][12][0], &sbuf[1][12][0], lane);
        else               prep_run<2>(gp, 14, &sbuf[0][14][0], &sbuf[1][14][0], lane);
    }
}

extern "C" void kernel_launch(void* const* d_in, const int* in_sizes, int n_in,
                              void* d_out, int out_size, void* d_ws, size_t ws_size,
                              hipStream_t stream) {
    const float* img = (const float*)d_in[0];
    float* out = (float*)d_out;
    dp_kernel<<<out_size, 448, 0, stream>>>(img, out);
}

// Round 22
// 43.212 us; speedup vs baseline: 1.0046x; 1.0046x over previous
//
#include <hip/hip_runtime.h>

// (min,+) DP, wave-specialized. R20 topology: 1 image/block, 7 waves,
// grid=512 (2/CU); wid3 = chain (SIMD3 pairs the two blocks' chains);
// 6 prep waves on SIMD0-2. Fused DPP scans.
// Tropical-factored chain (R21 math, verified exact) SOFTWARE-PIPELINED:
//   CONSUME: moff = shr(mm); m_i = fmin(E_i, moff + F_i)   [mm-dependent]
//   PREP(Sn): next row's E/F coefficients from (m, S)      [mm-INdependent]
//   SCAN: mm = dpp min-scan (volatile asm, LAST in each row)
// Order CONSUME->PREP->SCAN puts the scan's dependent-DPP stall at the
// row tail, where the OTHER chain wave on SIMD3 fills it (R21 had PREP
// wedged between moff and scan = pure added issue time -> regressed).

#define HH 256
#define WW 256
#define CH 16          // rows per chunk
#define NCH 16         // chunks per image
#define NULLV 1e30f

template<int CTRL, int ROWM>
__device__ __forceinline__ float dpp_mov(float x, float oldv) {
    return __builtin_bit_cast(float, __builtin_amdgcn_update_dpp(
        __builtin_bit_cast(int, oldv), __builtin_bit_cast(int, x),
        CTRL, ROWM, 0xF, false));
}

// 64-lane inclusive min-scan: 6 fused in-place DPP steps.
__device__ __forceinline__ float wave_iscan_min(float x) {
    asm volatile(
        "s_nop 1\n\t"
        "v_min_f32_dpp %0, %0, %0 row_shr:1  row_mask:0xf bank_mask:0xf\n\t"
        "s_nop 1\n\t"
        "v_min_f32_dpp %0, %0, %0 row_shr:2  row_mask:0xf bank_mask:0xf\n\t"
        "s_nop 1\n\t"
        "v_min_f32_dpp %0, %0, %0 row_shr:4  row_mask:0xf bank_mask:0xf\n\t"
        "s_nop 1\n\t"
        "v_min_f32_dpp %0, %0, %0 row_shr:8  row_mask:0xf bank_mask:0xf\n\t"
        "s_nop 1\n\t"
        "v_min_f32_dpp %0, %0, %0 row_bcast:15 row_mask:0xa bank_mask:0xf\n\t"
        "s_nop 1\n\t"
        "v_min_f32_dpp %0, %0, %0 row_bcast:31 row_mask:0xc bank_mask:0xf"
        : "+v"(x));
    return x;
}

// 64-lane inclusive add-scan (prep only).
__device__ __forceinline__ float wave_iscan_add(float x) {
    asm volatile(
        "s_nop 1\n\t"
        "v_add_f32_dpp %0, %0, %0 row_shr:1  row_mask:0xf bank_mask:0xf bound_ctrl:0\n\t"
        "s_nop 1\n\t"
        "v_add_f32_dpp %0, %0, %0 row_shr:2  row_mask:0xf bank_mask:0xf bound_ctrl:0\n\t"
        "s_nop 1\n\t"
        "v_add_f32_dpp %0, %0, %0 row_shr:4  row_mask:0xf bank_mask:0xf bound_ctrl:0\n\t"
        "s_nop 1\n\t"
        "v_add_f32_dpp %0, %0, %0 row_shr:8  row_mask:0xf bank_mask:0xf bound_ctrl:0\n\t"
        "s_nop 1\n\t"
        "v_add_f32_dpp %0, %0, %0 row_bcast:15 row_mask:0xa bank_mask:0xf bound_ctrl:0\n\t"
        "s_nop 1\n\t"
        "v_add_f32_dpp %0, %0, %0 row_bcast:31 row_mask:0xc bank_mask:0xf bound_ctrl:0"
        : "+v"(x));
    return x;
}

__device__ __forceinline__ float softplus_f(float x) {
    float ax = fabsf(x);
    float t  = __expf(-ax);
    return fmaxf(x, 0.0f) + __logf(1.0f + t);
}

__device__ __forceinline__ float4 prep_row(float4 c) {
    float t0 = softplus_f(c.x);
    float t1 = t0 + softplus_f(c.y);
    float t2 = t1 + softplus_f(c.z);
    float t3 = t2 + softplus_f(c.w);
    float s    = wave_iscan_add(t3);
    float soff = dpp_mov<0x138, 0xF>(s, 0.0f);  // wave_shr:1, lane0 -> 0
    return make_float4(soff + t0, soff + t1, soff + t2, soff + t3);
}

template<int NR>
__device__ __forceinline__ void load_rows(const float4* gp, int r0, float4* L) {
#pragma unroll
    for (int i = 0; i < NR; ++i) L[i] = gp[(size_t)(r0 + i) * 64];
}

template<int NR>
__device__ __forceinline__ void prep_store(const float4* L, float* dst, int lane) {
#pragma unroll
    for (int i = 0; i < NR; ++i)
        *reinterpret_cast<float4*>(&dst[i * WW + lane * 4]) = prep_row(L[i]);
}

template<int NR>
__device__ __forceinline__ void prep_run(const float4* gp, int row0,
                                         float* base0, float* base1, int lane) {
    float4 L[NR];
    load_rows<NR>(gp, CH + row0, L);           // chunk 1
    __syncthreads();                           // B0 (chunk 0 published by all)
    for (int k = 1; k < NCH; ++k) {
        float4 N[NR];
        if (k + 1 < NCH) load_rows<NR>(gp, (k + 1) * CH + row0, N);
        prep_store<NR>(L, (k & 1) ? base1 : base0, lane);
        __syncthreads();                       // Bk: chunk k ready
        if (k + 1 < NCH) {
#pragma unroll
            for (int i = 0; i < NR; ++i) L[i] = N[i];
        }
    }
}

__global__ __launch_bounds__(448, 2) void dp_kernel(const float* __restrict__ img,
                                                    float* __restrict__ out) {
    const int tid = threadIdx.x;
    const int wid = tid >> 6;                  // 0..6; wid3 = chain (SIMD3)
    const int lane = tid & 63;

    __shared__ __align__(16) float sbuf[2][CH][WW];   // 32 KB

    const float* gbase = img + (size_t)blockIdx.x * HH * WW;
    const float4* gp = reinterpret_cast<const float4*>(gbase) + lane;

    if (wid == 3) {
        // ---------------- chain wave: pipelined factored recurrence ----------------
        {   // cooperative chunk-0: rows 0-1
            float4 C[2];
            load_rows<2>(gp, 0, C);
            prep_store<2>(C, &sbuf[0][0][0], lane);
        }
        __syncthreads();                       // B0: chunk 0 ready
        __builtin_amdgcn_s_setprio(1);

        float4 SpN;  float soffn;              // staged S (row being prepped-from)
        float m0, m1, m2, m3, mm;
        float E0, E1, E2, E3, F0, F1, F2, F3;

        auto PREP = [&](const float4& Sn) {    // coeffs for the row AFTER SpN
            float u0 = SpN.x + m0, u1 = SpN.y + m1, u2 = SpN.z + m2, u3 = SpN.w + m3;
            float c1 = fminf(u1, u0), c2 = fminf(u2, u1), c3 = fminf(u3, u2);
            float d0 = fminf(SpN.x, soffn), d1 = fminf(SpN.y, SpN.x);
            float d2 = fminf(SpN.z, SpN.y), d3 = fminf(SpN.w, SpN.z);
            float so = dpp_mov<0x138, 0xF>(Sn.w, 0.0f);
            float e0 = u0 - so, e1 = c1 - Sn.x, e2 = c2 - Sn.y, e3 = c3 - Sn.z;
            float f0 = d0 - so, f1 = d1 - Sn.x, f2 = d2 - Sn.y, f3 = d3 - Sn.z;
            E0 = e0; E1 = fminf(e0, e1); E2 = fminf(E1, e2);
            E3 = fminf(E1, fminf(e2, e3));
            F0 = f0; F1 = fminf(f0, f1); F2 = fminf(F1, f2);
            F3 = fminf(F1, fminf(f2, f3));
            SpN = Sn; soffn = so;
        };
        auto CONSUME = [&]() {                 // the only mm-dependent code
            float moff = dpp_mov<0x138, 0xF>(mm, NULLV);
            m0 = fminf(E0, moff + F0); m1 = fminf(E1, moff + F1);
            m2 = fminf(E2, moff + F2); m3 = fminf(E3, moff + F3);
        };

#define ROW(SN)  do { CONSUME(); PREP(SN); mm = wave_iscan_min(m3); } while (0)
#define ROWL()   do { CONSUME();           mm = wave_iscan_min(m3); } while (0)
#define RD4(P, buf, r0)                                                  \
    P##0 = *reinterpret_cast<const float4*>(&(buf)[(r0) + 0][lane * 4]); \
    P##1 = *reinterpret_cast<const float4*>(&(buf)[(r0) + 1][lane * 4]); \
    P##2 = *reinterpret_cast<const float4*>(&(buf)[(r0) + 2][lane * 4]); \
    P##3 = *reinterpret_cast<const float4*>(&(buf)[(r0) + 3][lane * 4]);

        float4 A0, A1, A2, A3, B0, B1, B2, B3;

        // ---- chunk 0 (rows 0..15) ----
        {
            const float(*buf)[WW] = sbuf[0];
            RD4(A, buf, 0); RD4(B, buf, 4);
            SpN = A0; soffn = dpp_mov<0x138, 0xF>(A0.w, 0.0f);  // row-0 init
            m0 = m1 = m2 = m3 = 0.0f; mm = 0.0f;
            PREP(A1);                          // coeffs for row 1
            ROW(A2); ROW(A3); ROW(B0);         // rows 1,2,3
            RD4(A, buf, 8);
            ROW(B1); ROW(B2); ROW(B3);         // rows 4,5,6
            ROW(A0);                           // row 7 (preps row 8)
            RD4(B, buf, 12);
            ROW(A1); ROW(A2); ROW(A3);         // rows 8,9,10
            ROW(B0); ROW(B1); ROW(B2); ROW(B3);// rows 11,12,13,14
            ROWL();                            // row 15
        }
        // ---- chunks 1..15 ----
        for (int k = 1; k < NCH; ++k) {
            __syncthreads();                   // Bk: chunk k ready
            const float(*buf)[WW] = sbuf[k & 1];
            RD4(A, buf, 0); RD4(B, buf, 4);
            PREP(A0);                          // coeffs for chunk's row 0
            ROW(A1); ROW(A2); ROW(A3);         // rows 0,1,2
            ROW(B0);                           // row 3
            RD4(A, buf, 8);
            ROW(B1); ROW(B2); ROW(B3);         // rows 4,5,6
            ROW(A0);                           // row 7
            RD4(B, buf, 12);
            ROW(A1); ROW(A2); ROW(A3);         // rows 8,9,10
            ROW(B0); ROW(B1); ROW(B2); ROW(B3);// rows 11,12,13,14
            ROWL();                            // row 15
        }
#undef RD4
#undef ROW
#undef ROWL
        // v3[col 255] = S(255).w + mm  (SpN staged = S of row 255)
        if (lane == 63) out[blockIdx.x] = SpN.w + mm;
    } else {
        // ---------------- prep waves (wid 0,1,2,4,5,6) ----------------
        if (wid == 0) { float4 C[3]; load_rows<3>(gp,  2, C); prep_store<3>(C, &sbuf[0][ 2][0], lane); }
        else if (wid == 1) { float4 C[3]; load_rows<3>(gp,  5, C); prep_store<3>(C, &sbuf[0][ 5][0], lane); }
        else if (wid == 2) { float4 C[3]; load_rows<3>(gp,  8, C); prep_store<3>(C, &sbuf[0][ 8][0], lane); }
        else if (wid == 4) { float4 C[2]; load_rows<2>(gp, 11, C); prep_store<2>(C, &sbuf[0][11][0], lane); }
        else if (wid == 5) { float4 C[2]; load_rows<2>(gp, 13, C); prep_store<2>(C, &sbuf[0][13][0], lane); }
        else               { float4 C[1]; load_rows<1>(gp, 15, C); prep_store<1>(C, &sbuf[0][15][0], lane); }

        if (wid == 0)      prep_run<3>(gp,  0, &sbuf[0][ 0][0], &sbuf[1][ 0][0], lane);
        else if (wid == 1) prep_run<3>(gp,  3, &sbuf[0][ 3][0], &sbuf[1][ 3][0], lane);
        else if (wid == 2) prep_run<3>(gp,  6, &sbuf[0][ 6][0], &sbuf[1][ 6][0], lane);
        else if (wid == 4) prep_run<3>(gp,  9, &sbuf[0][ 9][0], &sbuf[1][ 9][0], lane);
        else if (wid == 5) prep_run<2>(gp, 12, &sbuf[0][12][0], &sbuf[1][12][0], lane);
        else               prep_run<2>(gp, 14, &sbuf[0][14][0], &sbuf[1][14][0], lane);
    }
}

extern "C" void kernel_launch(void* const* d_in, const int* in_sizes, int n_in,
                              void* d_out, int out_size, void* d_ws, size_t ws_size,
                              hipStream_t stream) {
    const float* img = (const float*)d_in[0];
    float* out = (float*)d_out;
    dp_kernel<<<out_size, 448, 0, stream>>>(img, out);
}